// Round 1
// baseline (2839.379 us; speedup 1.0000x reference)
//
#include <hip/hip_runtime.h>

#define B_N 16
#define S_N 577
#define D_N 1280
#define H_N 16
#define HD_N 80
#define HALF_N 40
#define M_N (B_N * S_N) /* 9232 */
#define K_N 1280

__device__ __forceinline__ float bf2f(unsigned short u) {
    union { unsigned int i; float f; } x; x.i = ((unsigned int)u) << 16; return x.f;
}
__device__ __forceinline__ unsigned short f2bf(float f) {
    union { unsigned int i; float f; } x; x.f = f;
    unsigned int r = x.i + 0x7FFFu + ((x.i >> 16) & 1u);
    return (unsigned short)(r >> 16);
}

// C = A(M,K) @ W(N,K)^T + bias, fused epilogue.
// MODE 0: q  (rotary, bf16 out, layout (B,H,S,HD))
// MODE 1: k  (rotary, bf16 out, layout (B,H,HD,S))  -- transposed for QK^T
// MODE 2: v  (bf16 out, layout (B,H,S,HD))
// MODE 3: out-proj (A is bf16 attn, fp32 out, layout (B,S,D))
template <int MODE>
__global__ __launch_bounds__(256) void gemm_kernel(
    const void* __restrict__ A_, const float* __restrict__ W,
    const float* __restrict__ bias, const float* __restrict__ cosb,
    const float* __restrict__ sinb, void* __restrict__ out_)
{
    __shared__ __align__(16) float As[16][68];
    __shared__ __align__(16) float Bs[16][68];

    const int tid = threadIdx.x;
    const int tx = tid & 15, ty = tid >> 4;
    const int m0 = blockIdx.y * 64, n0 = blockIdx.x * 64;

    const int lrow = tid >> 2;          // 0..63
    const int lcol = (tid & 3) << 2;    // 0,4,8,12

    const float* Af = (const float*)A_;
    const unsigned short* Ab = (const unsigned short*)A_;

    float acc[4][4] = {};

    const int mr = m0 + lrow;
    const int nr = n0 + lrow;

    for (int k0 = 0; k0 < K_N; k0 += 16) {
        float a0, a1, a2, a3;
        if (mr < M_N) {
            if (MODE == 3) {
                ushort4 u = *(const ushort4*)(Ab + (size_t)mr * K_N + k0 + lcol);
                a0 = bf2f(u.x); a1 = bf2f(u.y); a2 = bf2f(u.z); a3 = bf2f(u.w);
            } else {
                float4 u = *(const float4*)(Af + (size_t)mr * K_N + k0 + lcol);
                a0 = u.x; a1 = u.y; a2 = u.z; a3 = u.w;
            }
        } else { a0 = a1 = a2 = a3 = 0.f; }
        float4 w = *(const float4*)(W + (size_t)nr * K_N + k0 + lcol);

        As[lcol + 0][lrow] = a0;
        As[lcol + 1][lrow] = a1;
        As[lcol + 2][lrow] = a2;
        As[lcol + 3][lrow] = a3;
        Bs[lcol + 0][lrow] = w.x;
        Bs[lcol + 1][lrow] = w.y;
        Bs[lcol + 2][lrow] = w.z;
        Bs[lcol + 3][lrow] = w.w;
        __syncthreads();

        #pragma unroll
        for (int kk = 0; kk < 16; ++kk) {
            float4 av = *(const float4*)&As[kk][ty << 2];
            float4 bv = *(const float4*)&Bs[kk][tx << 2];
            float a[4] = {av.x, av.y, av.z, av.w};
            float b[4] = {bv.x, bv.y, bv.z, bv.w};
            #pragma unroll
            for (int i = 0; i < 4; ++i)
                #pragma unroll
                for (int j = 0; j < 4; ++j)
                    acc[i][j] += a[i] * b[j];
        }
        __syncthreads();
    }

    const int mbase = m0 + (ty << 2);
    const int nbase = n0 + (tx << 2);

    if (MODE == 3) {
        float* out = (float*)out_;
        #pragma unroll
        for (int i = 0; i < 4; ++i) {
            int m = mbase + i;
            if (m >= M_N) continue;
            float4 o;
            o.x = acc[i][0] + bias[nbase + 0];
            o.y = acc[i][1] + bias[nbase + 1];
            o.z = acc[i][2] + bias[nbase + 2];
            o.w = acc[i][3] + bias[nbase + 3];
            *(float4*)(out + (size_t)m * D_N + nbase) = o;
        }
    } else {
        unsigned short* out = (unsigned short*)out_;
        #pragma unroll
        for (int i = 0; i < 4; ++i) {
            int m = mbase + i;
            if (m >= M_N) continue;
            int b = m / S_N, s = m - b * S_N;
            #pragma unroll
            for (int j = 0; j < 4; j += 2) {
                int n = nbase + j;             // even -> hd even, pair inside
                int h = n / HD_N, hd = n - h * HD_N;
                float v0 = acc[i][j]     + bias[n];
                float v1 = acc[i][j + 1] + bias[n + 1];
                float r0, r1;
                if (MODE == 2) { r0 = v0; r1 = v1; }
                else {
                    float c  = cosb[s * HALF_N + (hd >> 1)];
                    float sn = sinb[s * HALF_N + (hd >> 1)];
                    r0 = v0 * c - v1 * sn;
                    r1 = v0 * sn + v1 * c;
                }
                if (MODE == 1) {
                    size_t base = ((size_t)(b * H_N + h) * HD_N + hd) * S_N + s;
                    out[base]       = f2bf(r0);
                    out[base + S_N] = f2bf(r1);
                } else {
                    size_t base = ((size_t)(b * H_N + h) * S_N + s) * HD_N + hd;
                    out[base]     = f2bf(r0);
                    out[base + 1] = f2bf(r1);
                }
            }
        }
    }
}

// One block per (bh, 8 q-rows). q:(B,H,S,HD) kT:(B,H,HD,S) v:(B,H,S,HD), all bf16.
__global__ __launch_bounds__(256) void attn_kernel(
    const unsigned short* __restrict__ q,
    const unsigned short* __restrict__ kT,
    const unsigned short* __restrict__ v,
    unsigned short* __restrict__ attn)
{
    __shared__ __align__(16) float qT[80][8];      // [d][r]
    __shared__ __align__(16) float pT[S_N][8];     // [t][r]
    __shared__ __align__(16) float part[3][80][8]; // [g][d][r]
    __shared__ float invsum[8];

    const int tid = threadIdx.x;
    const int bh = blockIdx.y;
    const int s0 = blockIdx.x * 8;

    // load 8 q rows (transposed)
    for (int i = tid; i < 640; i += 256) {
        int r = i / 80, d = i - r * 80;
        int s = s0 + r;
        qT[d][r] = (s < S_N) ? bf2f(q[((size_t)bh * S_N + s) * HD_N + d]) : 0.f;
    }
    __syncthreads();

    // scores: each thread one key t per chunk, 8 rows
    const float scale = 0.11180339887498949f; // 1/sqrt(80)
    for (int c = 0; c < 3; ++c) {
        int t = c * 256 + tid;
        int tc = (t < S_N) ? t : (S_N - 1);
        const unsigned short* kp = kT + (size_t)bh * HD_N * S_N + tc;
        float acc[8] = {};
        #pragma unroll 4
        for (int d = 0; d < 80; ++d) {
            float kv = bf2f(kp[(size_t)d * S_N]);
            float4 qa = *(const float4*)&qT[d][0];
            float4 qb = *(const float4*)&qT[d][4];
            acc[0] += qa.x * kv; acc[1] += qa.y * kv;
            acc[2] += qa.z * kv; acc[3] += qa.w * kv;
            acc[4] += qb.x * kv; acc[5] += qb.y * kv;
            acc[6] += qb.z * kv; acc[7] += qb.w * kv;
        }
        if (t < S_N) {
            float4 pa = {acc[0] * scale, acc[1] * scale, acc[2] * scale, acc[3] * scale};
            float4 pb = {acc[4] * scale, acc[5] * scale, acc[6] * scale, acc[7] * scale};
            *(float4*)&pT[t][0] = pa;
            *(float4*)&pT[t][4] = pb;
        }
    }
    __syncthreads();

    // softmax per row: wave w handles rows 2w, 2w+1
    const int w = tid >> 6, lane = tid & 63;
    for (int rr = 0; rr < 2; ++rr) {
        int r = (w << 1) + rr;
        float mx = -1e30f;
        for (int t = lane; t < S_N; t += 64) mx = fmaxf(mx, pT[t][r]);
        #pragma unroll
        for (int off = 32; off; off >>= 1) mx = fmaxf(mx, __shfl_xor(mx, off));
        float sm = 0.f;
        for (int t = lane; t < S_N; t += 64) {
            float e = __expf(pT[t][r] - mx);
            pT[t][r] = e;
            sm += e;
        }
        #pragma unroll
        for (int off = 32; off; off >>= 1) sm += __shfl_xor(sm, off);
        if (lane == 0) invsum[r] = 1.f / sm;
    }
    __syncthreads();

    // PV: 3 t-groups x 80 dims
    if (tid < 240) {
        int g = tid / 80, d = tid - g * 80;
        const unsigned short* vp = v + (size_t)bh * S_N * HD_N + d;
        float acc[8] = {};
        for (int t = g; t < S_N; t += 3) {
            float vv = bf2f(vp[(size_t)t * HD_N]);
            float4 pa = *(const float4*)&pT[t][0];
            float4 pb = *(const float4*)&pT[t][4];
            acc[0] += pa.x * vv; acc[1] += pa.y * vv;
            acc[2] += pa.z * vv; acc[3] += pa.w * vv;
            acc[4] += pb.x * vv; acc[5] += pb.y * vv;
            acc[6] += pb.z * vv; acc[7] += pb.w * vv;
        }
        float4 o0 = {acc[0], acc[1], acc[2], acc[3]};
        float4 o1 = {acc[4], acc[5], acc[6], acc[7]};
        *(float4*)&part[g][d][0] = o0;
        *(float4*)&part[g][d][4] = o1;
    }
    __syncthreads();

    // combine + store attn (B,S,D) bf16
    const int b = bh >> 4, h = bh & 15;
    for (int i = tid; i < 640; i += 256) {
        int r = i / 80, d = i - r * 80;
        int s = s0 + r;
        if (s < S_N) {
            float o = (part[0][d][r] + part[1][d][r] + part[2][d][r]) * invsum[r];
            attn[((size_t)b * S_N + s) * D_N + h * HD_N + d] = f2bf(o);
        }
    }
}

extern "C" void kernel_launch(void* const* d_in, const int* in_sizes, int n_in,
                              void* d_out, int out_size, void* d_ws, size_t ws_size,
                              hipStream_t stream) {
    const float* hs = (const float*)d_in[0];
    const float* fc = (const float*)d_in[1];
    const float* fs = (const float*)d_in[2];
    const float* Wq = (const float*)d_in[3];
    const float* bq = (const float*)d_in[4];
    const float* Wk = (const float*)d_in[5];
    const float* bk = (const float*)d_in[6];
    const float* Wv = (const float*)d_in[7];
    const float* bv = (const float*)d_in[8];
    const float* Wo = (const float*)d_in[9];
    const float* bo = (const float*)d_in[10];
    float* out = (float*)d_out;

    char* ws = (char*)d_ws;
    const size_t qkv_bytes = (size_t)M_N * D_N * 2; // 23,633,920 B, 256-aligned
    unsigned short* q  = (unsigned short*)(ws);
    unsigned short* kT = (unsigned short*)(ws + qkv_bytes);
    unsigned short* v  = (unsigned short*)(ws + 2 * qkv_bytes);
    unsigned short* at = (unsigned short*)(ws + 3 * qkv_bytes);

    dim3 blk(256);
    dim3 ggrid(D_N / 64, (M_N + 63) / 64); // 20 x 145

    gemm_kernel<0><<<ggrid, blk, 0, stream>>>(hs, Wq, bq, fc, fs, q);
    gemm_kernel<1><<<ggrid, blk, 0, stream>>>(hs, Wk, bk, fc, fs, kT);
    gemm_kernel<2><<<ggrid, blk, 0, stream>>>(hs, Wv, bv, fc, fs, v);

    attn_kernel<<<dim3((S_N + 7) / 8, B_N * H_N), blk, 0, stream>>>(q, kT, v, at);

    gemm_kernel<3><<<ggrid, blk, 0, stream>>>(at, Wo, bo, fc, fs, out);
}

// Round 2
// 1951.454 us; speedup vs baseline: 1.4550x; 1.4550x over previous
//
#include <hip/hip_runtime.h>

#define B_N 16
#define S_N 577
#define D_N 1280
#define H_N 16
#define HD_N 80
#define HALF_N 40
#define M_N (B_N * S_N) /* 9232 */
#define K_N 1280
#define VT_S 592          /* padded t-stride for VT (multiple of 16 elems -> 16B aligned frags) */
#define QSCALE 0.11180339887498949f /* 1/sqrt(80) */

typedef __bf16 bf16_t;
typedef bf16_t bf16x8 __attribute__((ext_vector_type(8)));
typedef float f32x4 __attribute__((ext_vector_type(4)));

__device__ __forceinline__ float bf2f(unsigned short u) {
    union { unsigned int i; float f; } x; x.i = ((unsigned int)u) << 16; return x.f;
}
__device__ __forceinline__ unsigned short f2bf(float f) {
    union { unsigned int i; float f; } x; x.f = f;
    unsigned int r = x.i + 0x7FFFu + ((x.i >> 16) & 1u);
    return (unsigned short)(r >> 16);
}

// C = A(M,K) @ W(N,K)^T + bias, fused epilogue.
// MODE 0: q  (rotary, *QSCALE, bf16, layout (B,H,S,HD))
// MODE 1: k  (rotary, bf16, layout (B,H,S,HD))
// MODE 2: v  (bf16, layout (B,H,HD,VT_S) transposed, padded t-stride)
// MODE 3: out-proj (A is bf16 attn, fp32 out, layout (B,S,D))
template <int MODE>
__global__ __launch_bounds__(256) void gemm_kernel(
    const void* __restrict__ A_, const float* __restrict__ W,
    const float* __restrict__ bias, const float* __restrict__ cosb,
    const float* __restrict__ sinb, void* __restrict__ out_)
{
    __shared__ __align__(16) float As[16][68];
    __shared__ __align__(16) float Bs[16][68];

    const int tid = threadIdx.x;
    const int tx = tid & 15, ty = tid >> 4;
    const int m0 = blockIdx.y * 64, n0 = blockIdx.x * 64;

    const int lrow = tid >> 2;          // 0..63
    const int lcol = (tid & 3) << 2;    // 0,4,8,12

    const float* Af = (const float*)A_;
    const unsigned short* Ab = (const unsigned short*)A_;

    float acc[4][4] = {};

    const int mr = m0 + lrow;
    const int nr = n0 + lrow;

    for (int k0 = 0; k0 < K_N; k0 += 16) {
        float a0, a1, a2, a3;
        if (mr < M_N) {
            if (MODE == 3) {
                ushort4 u = *(const ushort4*)(Ab + (size_t)mr * K_N + k0 + lcol);
                a0 = bf2f(u.x); a1 = bf2f(u.y); a2 = bf2f(u.z); a3 = bf2f(u.w);
            } else {
                float4 u = *(const float4*)(Af + (size_t)mr * K_N + k0 + lcol);
                a0 = u.x; a1 = u.y; a2 = u.z; a3 = u.w;
            }
        } else { a0 = a1 = a2 = a3 = 0.f; }
        float4 w = *(const float4*)(W + (size_t)nr * K_N + k0 + lcol);

        As[lcol + 0][lrow] = a0;
        As[lcol + 1][lrow] = a1;
        As[lcol + 2][lrow] = a2;
        As[lcol + 3][lrow] = a3;
        Bs[lcol + 0][lrow] = w.x;
        Bs[lcol + 1][lrow] = w.y;
        Bs[lcol + 2][lrow] = w.z;
        Bs[lcol + 3][lrow] = w.w;
        __syncthreads();

        #pragma unroll
        for (int kk = 0; kk < 16; ++kk) {
            float4 av = *(const float4*)&As[kk][ty << 2];
            float4 bv = *(const float4*)&Bs[kk][tx << 2];
            float a[4] = {av.x, av.y, av.z, av.w};
            float b[4] = {bv.x, bv.y, bv.z, bv.w};
            #pragma unroll
            for (int i = 0; i < 4; ++i)
                #pragma unroll
                for (int j = 0; j < 4; ++j)
                    acc[i][j] += a[i] * b[j];
        }
        __syncthreads();
    }

    const int mbase = m0 + (ty << 2);
    const int nbase = n0 + (tx << 2);

    if (MODE == 3) {
        float* out = (float*)out_;
        #pragma unroll
        for (int i = 0; i < 4; ++i) {
            int m = mbase + i;
            if (m >= M_N) continue;
            float4 o;
            o.x = acc[i][0] + bias[nbase + 0];
            o.y = acc[i][1] + bias[nbase + 1];
            o.z = acc[i][2] + bias[nbase + 2];
            o.w = acc[i][3] + bias[nbase + 3];
            *(float4*)(out + (size_t)m * D_N + nbase) = o;
        }
    } else {
        unsigned short* out = (unsigned short*)out_;
        #pragma unroll
        for (int i = 0; i < 4; ++i) {
            int m = mbase + i;
            if (m >= M_N) continue;
            int b = m / S_N, s = m - b * S_N;
            #pragma unroll
            for (int j = 0; j < 4; j += 2) {
                int nn = nbase + j;            // even -> hd even, rotary pair inside
                int h = nn / HD_N, hd = nn - h * HD_N;
                float v0 = acc[i][j]     + bias[nn];
                float v1 = acc[i][j + 1] + bias[nn + 1];
                float r0, r1;
                if (MODE == 2) { r0 = v0; r1 = v1; }
                else {
                    float c  = cosb[s * HALF_N + (hd >> 1)];
                    float sn = sinb[s * HALF_N + (hd >> 1)];
                    r0 = v0 * c - v1 * sn;
                    r1 = v0 * sn + v1 * c;
                    if (MODE == 0) { r0 *= QSCALE; r1 *= QSCALE; }
                }
                if (MODE == 2) {
                    size_t base = ((size_t)(b * H_N + h) * HD_N + hd) * VT_S + s;
                    out[base]        = f2bf(r0);
                    out[base + VT_S] = f2bf(r1);
                } else {
                    size_t base = ((size_t)(b * H_N + h) * S_N + s) * HD_N + hd;
                    out[base]     = f2bf(r0);
                    out[base + 1] = f2bf(r1);
                }
            }
        }
    }
}

// MFMA flash attention. Block = 4 independent waves, each owns 16 q-rows.
// q,k: (B,H,S,HD) bf16. vt: (B,H,HD,VT_S) bf16. attn out: (B,S,D) bf16.
// No __syncthreads anywhere; per-wave LDS P-buffer for C->A layout transform.
__global__ __launch_bounds__(256) void fattn_kernel(
    const unsigned short* __restrict__ qb,
    const unsigned short* __restrict__ kb,
    const unsigned short* __restrict__ vt,
    unsigned short* __restrict__ attn)
{
    __shared__ __align__(16) unsigned short Plds[4][16][32];

    const int tid = threadIdx.x;
    const int wave = tid >> 6, lane = tid & 63;
    const int quad = lane >> 4, n = lane & 15;
    const int bh = blockIdx.y;
    const int q0 = blockIdx.x * 64 + wave * 16;

    // A-operand Q fragments (loop-invariant): row = q0+n, k = ks + quad*8..+8
    const unsigned short* qrow = qb + ((size_t)bh * S_N + q0 + n) * HD_N;
    const bf16x8 zf{};
    bf16x8 aq0 = *(const bf16x8*)(qrow + quad * 8);
    bf16x8 aq1 = *(const bf16x8*)(qrow + 32 + quad * 8);
    bf16x8 aq2 = (quad < 2) ? *(const bf16x8*)(qrow + 64 + quad * 8) : zf;

    float m[4] = {-1e30f, -1e30f, -1e30f, -1e30f};
    float l[4] = {};
    f32x4 o[5] = {};

    const unsigned short* kbase = kb + (size_t)bh * S_N * HD_N;
    const unsigned short* vbase = vt + (size_t)bh * HD_N * VT_S;
    unsigned short* pl = &Plds[wave][0][0];

    const bool mA0 = false; // placeholder (mask computed per tile)

    for (int t0 = 0; t0 < 608; t0 += 32) {
        // ---- QK^T: two 16x16 score tiles (keys t0..t0+31) ----
        f32x4 c0{}, c1{};
        {
            const unsigned short* kr = kbase + (size_t)(t0 + n) * HD_N;
            bf16x8 b0 = *(const bf16x8*)(kr + quad * 8);
            bf16x8 b1 = *(const bf16x8*)(kr + 32 + quad * 8);
            bf16x8 b2 = (quad < 2) ? *(const bf16x8*)(kr + 64 + quad * 8) : zf;
            c0 = __builtin_amdgcn_mfma_f32_16x16x32_bf16(aq0, b0, c0, 0, 0, 0);
            c0 = __builtin_amdgcn_mfma_f32_16x16x32_bf16(aq1, b1, c0, 0, 0, 0);
            c0 = __builtin_amdgcn_mfma_f32_16x16x32_bf16(aq2, b2, c0, 0, 0, 0);
        }
        {
            const unsigned short* kr = kbase + (size_t)(t0 + 16 + n) * HD_N;
            bf16x8 b0 = *(const bf16x8*)(kr + quad * 8);
            bf16x8 b1 = *(const bf16x8*)(kr + 32 + quad * 8);
            bf16x8 b2 = (quad < 2) ? *(const bf16x8*)(kr + 64 + quad * 8) : zf;
            c1 = __builtin_amdgcn_mfma_f32_16x16x32_bf16(aq0, b0, c1, 0, 0, 0);
            c1 = __builtin_amdgcn_mfma_f32_16x16x32_bf16(aq1, b1, c1, 0, 0, 0);
            c1 = __builtin_amdgcn_mfma_f32_16x16x32_bf16(aq2, b2, c1, 0, 0, 0);
        }

        const bool mA = (t0 + n) >= S_N;
        const bool mB = (t0 + 16 + n) >= S_N;

        // ---- online softmax update (C rows = quad*4+r, col = n) ----
        float alpha[4];
        #pragma unroll
        for (int r = 0; r < 4; ++r) {
            float s0 = mA ? -1e30f : c0[r];
            float s1 = mB ? -1e30f : c1[r];
            float mx = fmaxf(s0, s1);
            mx = fmaxf(mx, __shfl_xor(mx, 1));
            mx = fmaxf(mx, __shfl_xor(mx, 2));
            mx = fmaxf(mx, __shfl_xor(mx, 4));
            mx = fmaxf(mx, __shfl_xor(mx, 8));
            float mn = fmaxf(m[r], mx);
            float al = __expf(m[r] - mn);
            m[r] = mn;
            float p0 = __expf(s0 - mn);
            float p1 = __expf(s1 - mn);
            float rs = p0 + p1;
            rs += __shfl_xor(rs, 1);
            rs += __shfl_xor(rs, 2);
            rs += __shfl_xor(rs, 4);
            rs += __shfl_xor(rs, 8);
            l[r] = l[r] * al + rs;
            alpha[r] = al;
            pl[(quad * 4 + r) * 32 + n]      = f2bf(p0);
            pl[(quad * 4 + r) * 32 + 16 + n] = f2bf(p1);
        }

        // ---- rescale O, then PV over this 32-key slab ----
        #pragma unroll
        for (int nt = 0; nt < 5; ++nt)
            #pragma unroll
            for (int r = 0; r < 4; ++r)
                o[nt][r] *= alpha[r];

        // A-frag from per-wave P (same-wave LDS RAW: DS pipe is in-order)
        bf16x8 ap = *(const bf16x8*)(pl + n * 32 + quad * 8);
        #pragma unroll
        for (int nt = 0; nt < 5; ++nt) {
            const unsigned short* vr = vbase + (size_t)(nt * 16 + n) * VT_S + t0 + quad * 8;
            bf16x8 bv = *(const bf16x8*)vr;
            o[nt] = __builtin_amdgcn_mfma_f32_16x16x32_bf16(ap, bv, o[nt], 0, 0, 0);
        }
    }

    // ---- epilogue: O /= l, store (B,S,D) bf16 ----
    const int b = bh >> 4, h = bh & 15;
    float linv[4];
    #pragma unroll
    for (int r = 0; r < 4; ++r) linv[r] = 1.0f / l[r];
    #pragma unroll
    for (int nt = 0; nt < 5; ++nt)
        #pragma unroll
        for (int r = 0; r < 4; ++r) {
            int s = q0 + quad * 4 + r;
            if (s < S_N)
                attn[((size_t)b * S_N + s) * D_N + h * HD_N + nt * 16 + n] =
                    f2bf(o[nt][r] * linv[r]);
        }
    (void)mA0;
}

extern "C" void kernel_launch(void* const* d_in, const int* in_sizes, int n_in,
                              void* d_out, int out_size, void* d_ws, size_t ws_size,
                              hipStream_t stream) {
    const float* hs = (const float*)d_in[0];
    const float* fc = (const float*)d_in[1];
    const float* fs = (const float*)d_in[2];
    const float* Wq = (const float*)d_in[3];
    const float* bq = (const float*)d_in[4];
    const float* Wk = (const float*)d_in[5];
    const float* bk = (const float*)d_in[6];
    const float* Wv = (const float*)d_in[7];
    const float* bv = (const float*)d_in[8];
    const float* Wo = (const float*)d_in[9];
    const float* bo = (const float*)d_in[10];
    float* out = (float*)d_out;

    char* ws = (char*)d_ws;
    const size_t qk_bytes = (size_t)M_N * D_N * 2;              // 23,633,920 B
    const size_t vt_bytes = (size_t)B_N * H_N * HD_N * VT_S * 2; // 24,248,320 B
    unsigned short* q  = (unsigned short*)(ws);
    unsigned short* k  = (unsigned short*)(ws + qk_bytes);
    unsigned short* vt = (unsigned short*)(ws + 2 * qk_bytes);
    unsigned short* at = (unsigned short*)(ws + 2 * qk_bytes + vt_bytes);

    dim3 blk(256);
    dim3 ggrid(D_N / 64, (M_N + 63) / 64); // 20 x 145

    gemm_kernel<0><<<ggrid, blk, 0, stream>>>(hs, Wq, bq, fc, fs, q);
    gemm_kernel<1><<<ggrid, blk, 0, stream>>>(hs, Wk, bk, fc, fs, k);
    gemm_kernel<2><<<ggrid, blk, 0, stream>>>(hs, Wv, bv, fc, fs, vt);

    fattn_kernel<<<dim3(10, B_N * H_N), blk, 0, stream>>>(q, k, vt, at);

    gemm_kernel<3><<<ggrid, blk, 0, stream>>>(at, Wo, bo, fc, fs, out);
}

// Round 3
// 504.205 us; speedup vs baseline: 5.6314x; 3.8704x over previous
//
#include <hip/hip_runtime.h>

#define B_N 16
#define S_N 577
#define D_N 1280
#define H_N 16
#define HD_N 80
#define HALF_N 40
#define M_N 9232
#define M_PAD 9344
#define K_N 1280
#define VT_S 608
#define QSCALE 0.11180339887498949f /* 1/sqrt(80) */

typedef __bf16 bf16_t;
typedef bf16_t bf16x8 __attribute__((ext_vector_type(8)));
typedef float f32x4 __attribute__((ext_vector_type(4)));

__device__ __forceinline__ float bf2f(unsigned short u) {
    union { unsigned int i; float f; } x; x.i = ((unsigned int)u) << 16; return x.f;
}
__device__ __forceinline__ unsigned short f2bf(float f) {
    union { unsigned int i; float f; } x; x.f = f;
    unsigned int r = x.i + 0x7FFFu + ((x.i >> 16) & 1u);
    return (unsigned short)(r >> 16);
}

__device__ __forceinline__ void gld_lds16(const unsigned short* g, unsigned short* l) {
    __builtin_amdgcn_global_load_lds(
        (const __attribute__((address_space(1))) unsigned int*)g,
        (__attribute__((address_space(3))) unsigned int*)l,
        16, 0, 0);
}

// fp32 -> bf16 (RNE), vectorized x4
__global__ __launch_bounds__(256) void cvt_kernel(const float* __restrict__ in,
                                                  unsigned short* __restrict__ out, int n4) {
    int i = blockIdx.x * 256 + threadIdx.x;
    if (i < n4) {
        float4 v = ((const float4*)in)[i];
        ushort4 o;
        o.x = f2bf(v.x); o.y = f2bf(v.y); o.z = f2bf(v.z); o.w = f2bf(v.w);
        ((ushort4*)out)[i] = o;
    }
}

// MFMA GEMM: C(M,N) = A(M,K) @ W(N,K)^T + bias, fused epilogue.
// A, W bf16 row-major (K contiguous). 128x128 tile, BK=32, 4 waves 2x2.
// MODE 0: q (rotary, *QSCALE, bf16 out (B,H,S,HD))
// MODE 1: k (rotary, bf16 out (B,H,S,HD))
// MODE 2: v (bf16 out (B,H,HD,VT_S) transposed)
// MODE 3: out-proj (fp32 out (B,S,D))
template <int MODE>
__global__ __launch_bounds__(256) void mgemm_kernel(
    const unsigned short* __restrict__ A,
    const unsigned short* __restrict__ Wb,
    const float* __restrict__ bias,
    const float* __restrict__ cosb, const float* __restrict__ sinb,
    void* __restrict__ out_)
{
    __shared__ __align__(16) unsigned short As[128 * 32];
    __shared__ __align__(16) unsigned short Bs[128 * 32];

    const int tid = threadIdx.x;
    const int wave = tid >> 6, lane = tid & 63;
    const int quad = lane >> 4, n = lane & 15;
    const int wm = wave >> 1, wn = wave & 1;
    const int m0 = blockIdx.y * 128, n0 = blockIdx.x * 128;

    const int ldrow = lane >> 2;       // 0..15
    const int ldk = (lane & 3) * 8;    // 0,8,16,24

    const unsigned short* gA = A + (size_t)(m0 + wave * 32 + ldrow) * K_N + ldk;
    const unsigned short* gB = Wb + (size_t)(n0 + wave * 32 + ldrow) * K_N + ldk;
    unsigned short* lA = As + wave * 32 * 32;
    unsigned short* lB = Bs + wave * 32 * 32;

    f32x4 acc[4][4] = {};

    for (int k0 = 0; k0 < K_N; k0 += 32) {
        gld_lds16(gA + k0, lA);
        gld_lds16(gA + k0 + 16 * K_N, lA + 16 * 32);
        gld_lds16(gB + k0, lB);
        gld_lds16(gB + k0 + 16 * K_N, lB + 16 * 32);
        __syncthreads();   // drains vmcnt -> LDS valid

        bf16x8 af[4], bfr[4];
        #pragma unroll
        for (int mt = 0; mt < 4; ++mt)
            af[mt] = *(const bf16x8*)&As[(wm * 64 + mt * 16 + n) * 32 + quad * 8];
        #pragma unroll
        for (int nt = 0; nt < 4; ++nt)
            bfr[nt] = *(const bf16x8*)&Bs[(wn * 64 + nt * 16 + n) * 32 + quad * 8];
        #pragma unroll
        for (int mt = 0; mt < 4; ++mt)
            #pragma unroll
            for (int nt = 0; nt < 4; ++nt)
                acc[mt][nt] = __builtin_amdgcn_mfma_f32_16x16x32_bf16(
                    af[mt], bfr[nt], acc[mt][nt], 0, 0, 0);
        __syncthreads();   // all waves done reading before next overwrite
    }

    const int nbase = n0 + wn * 64;
    const int mbase = m0 + wm * 64;

    if (MODE == 3) {
        float* out = (float*)out_;
        #pragma unroll
        for (int mt = 0; mt < 4; ++mt)
            #pragma unroll
            for (int nt = 0; nt < 4; ++nt) {
                const int ncol = nbase + nt * 16 + n;
                const float bv = bias[ncol];
                #pragma unroll
                for (int r = 0; r < 4; ++r) {
                    int mrow = mbase + mt * 16 + quad * 4 + r;
                    if (mrow < M_N)
                        out[(size_t)mrow * D_N + ncol] = acc[mt][nt][r] + bv;
                }
            }
    } else {
        unsigned short* out = (unsigned short*)out_;
        const bool evn = (n & 1) == 0;
        #pragma unroll
        for (int nt = 0; nt < 4; ++nt) {
            const int ncol = nbase + nt * 16 + n;
            const int h = ncol / HD_N, hd = ncol - h * HD_N;
            const float bv = bias[ncol];
            #pragma unroll
            for (int mt = 0; mt < 4; ++mt)
                #pragma unroll
                for (int r = 0; r < 4; ++r) {
                    int mrow = mbase + mt * 16 + quad * 4 + r;
                    int b = mrow / S_N, s = mrow - b * S_N;
                    float v = acc[mt][nt][r] + bv;
                    float res;
                    if (MODE == 2) {
                        res = v;
                    } else {
                        float pv = __shfl_xor(v, 1);  // paired column (ncol^1)
                        float c  = cosb[s * HALF_N + (hd >> 1)];
                        float sn = sinb[s * HALF_N + (hd >> 1)];
                        res = evn ? (v * c - pv * sn) : (pv * sn + v * c);
                        if (MODE == 0) res *= QSCALE;
                    }
                    if (mrow < M_N) {
                        if (MODE == 2)
                            out[((size_t)(b * H_N + h) * HD_N + hd) * VT_S + s] = f2bf(res);
                        else
                            out[((size_t)(b * H_N + h) * S_N + s) * HD_N + hd] = f2bf(res);
                    }
                }
        }
    }
}

// MFMA flash attention. Block = 4 independent waves, each owns 16 q-rows.
// q,k: (B,H,S,HD) bf16. vt: (B,H,HD,VT_S) bf16. attn out: (B,S,D) bf16.
__global__ __launch_bounds__(256) void fattn_kernel(
    const unsigned short* __restrict__ qb,
    const unsigned short* __restrict__ kb,
    const unsigned short* __restrict__ vt,
    unsigned short* __restrict__ attn)
{
    __shared__ __align__(16) unsigned short Plds[4][16][32];

    const int tid = threadIdx.x;
    const int wave = tid >> 6, lane = tid & 63;
    const int quad = lane >> 4, n = lane & 15;
    const int bh = blockIdx.y;
    const int q0 = blockIdx.x * 64 + wave * 16;

    const unsigned short* qrow = qb + ((size_t)bh * S_N + q0 + n) * HD_N;
    const bf16x8 zf{};
    bf16x8 aq0 = *(const bf16x8*)(qrow + quad * 8);
    bf16x8 aq1 = *(const bf16x8*)(qrow + 32 + quad * 8);
    bf16x8 aq2 = (quad < 2) ? *(const bf16x8*)(qrow + 64 + quad * 8) : zf;

    float m[4] = {-1e30f, -1e30f, -1e30f, -1e30f};
    float l[4] = {};
    f32x4 o[5] = {};

    const unsigned short* kbase = kb + (size_t)bh * S_N * HD_N;
    const unsigned short* vbase = vt + (size_t)bh * HD_N * VT_S;
    unsigned short* pl = &Plds[wave][0][0];

    for (int t0 = 0; t0 < 608; t0 += 32) {
        f32x4 c0{}, c1{};
        {
            const unsigned short* kr = kbase + (size_t)(t0 + n) * HD_N;
            bf16x8 b0 = *(const bf16x8*)(kr + quad * 8);
            bf16x8 b1 = *(const bf16x8*)(kr + 32 + quad * 8);
            bf16x8 b2 = (quad < 2) ? *(const bf16x8*)(kr + 64 + quad * 8) : zf;
            c0 = __builtin_amdgcn_mfma_f32_16x16x32_bf16(aq0, b0, c0, 0, 0, 0);
            c0 = __builtin_amdgcn_mfma_f32_16x16x32_bf16(aq1, b1, c0, 0, 0, 0);
            c0 = __builtin_amdgcn_mfma_f32_16x16x32_bf16(aq2, b2, c0, 0, 0, 0);
        }
        {
            const unsigned short* kr = kbase + (size_t)(t0 + 16 + n) * HD_N;
            bf16x8 b0 = *(const bf16x8*)(kr + quad * 8);
            bf16x8 b1 = *(const bf16x8*)(kr + 32 + quad * 8);
            bf16x8 b2 = (quad < 2) ? *(const bf16x8*)(kr + 64 + quad * 8) : zf;
            c1 = __builtin_amdgcn_mfma_f32_16x16x32_bf16(aq0, b0, c1, 0, 0, 0);
            c1 = __builtin_amdgcn_mfma_f32_16x16x32_bf16(aq1, b1, c1, 0, 0, 0);
            c1 = __builtin_amdgcn_mfma_f32_16x16x32_bf16(aq2, b2, c1, 0, 0, 0);
        }

        const bool mA = (t0 + n) >= S_N;
        const bool mB = (t0 + 16 + n) >= S_N;

        float alpha[4];
        #pragma unroll
        for (int r = 0; r < 4; ++r) {
            float s0 = mA ? -1e30f : c0[r];
            float s1 = mB ? -1e30f : c1[r];
            float mx = fmaxf(s0, s1);
            mx = fmaxf(mx, __shfl_xor(mx, 1));
            mx = fmaxf(mx, __shfl_xor(mx, 2));
            mx = fmaxf(mx, __shfl_xor(mx, 4));
            mx = fmaxf(mx, __shfl_xor(mx, 8));
            float mn = fmaxf(m[r], mx);
            float al = __expf(m[r] - mn);
            m[r] = mn;
            float p0 = __expf(s0 - mn);
            float p1 = __expf(s1 - mn);
            float rs = p0 + p1;
            rs += __shfl_xor(rs, 1);
            rs += __shfl_xor(rs, 2);
            rs += __shfl_xor(rs, 4);
            rs += __shfl_xor(rs, 8);
            l[r] = l[r] * al + rs;
            alpha[r] = al;
            pl[(quad * 4 + r) * 32 + n]      = f2bf(p0);
            pl[(quad * 4 + r) * 32 + 16 + n] = f2bf(p1);
        }

        #pragma unroll
        for (int nt = 0; nt < 5; ++nt)
            #pragma unroll
            for (int r = 0; r < 4; ++r)
                o[nt][r] *= alpha[r];

        bf16x8 ap = *(const bf16x8*)(pl + n * 32 + quad * 8);
        #pragma unroll
        for (int nt = 0; nt < 5; ++nt) {
            const unsigned short* vr = vbase + (size_t)(nt * 16 + n) * VT_S + t0 + quad * 8;
            bf16x8 bv = *(const bf16x8*)vr;
            o[nt] = __builtin_amdgcn_mfma_f32_16x16x32_bf16(ap, bv, o[nt], 0, 0, 0);
        }
    }

    const int b = bh >> 4, h = bh & 15;
    float linv[4];
    #pragma unroll
    for (int r = 0; r < 4; ++r) linv[r] = 1.0f / l[r];
    #pragma unroll
    for (int nt = 0; nt < 5; ++nt)
        #pragma unroll
        for (int r = 0; r < 4; ++r) {
            int s = q0 + quad * 4 + r;
            if (s < S_N)
                attn[((size_t)b * S_N + s) * D_N + h * HD_N + nt * 16 + n] =
                    f2bf(o[nt][r] * linv[r]);
        }
}

extern "C" void kernel_launch(void* const* d_in, const int* in_sizes, int n_in,
                              void* d_out, int out_size, void* d_ws, size_t ws_size,
                              hipStream_t stream) {
    const float* hs = (const float*)d_in[0];
    const float* fc = (const float*)d_in[1];
    const float* fs = (const float*)d_in[2];
    const float* Wq = (const float*)d_in[3];
    const float* bq = (const float*)d_in[4];
    const float* Wk = (const float*)d_in[5];
    const float* bk = (const float*)d_in[6];
    const float* Wv = (const float*)d_in[7];
    const float* bv = (const float*)d_in[8];
    const float* Wo = (const float*)d_in[9];
    const float* bo = (const float*)d_in[10];
    float* out = (float*)d_out;

    char* ws = (char*)d_ws;
    size_t off = 0;
    auto alloc = [&](size_t bytes) {
        char* p = ws + off; off += (bytes + 255) & ~(size_t)255; return p;
    };
    unsigned short* hsb = (unsigned short*)alloc((size_t)M_PAD * K_N * 2); // aliased as 'at' later
    unsigned short* qb  = (unsigned short*)alloc((size_t)M_N * K_N * 2 + 32768);
    unsigned short* kb  = (unsigned short*)alloc((size_t)M_N * K_N * 2 + 32768);
    unsigned short* vt  = (unsigned short*)alloc((size_t)B_N * H_N * HD_N * VT_S * 2);
    unsigned short* W0  = (unsigned short*)alloc((size_t)D_N * K_N * 2);
    unsigned short* W1  = (unsigned short*)alloc((size_t)D_N * K_N * 2);

    const int HS4 = M_N * K_N / 4;   // 2,954,240
    const int W4  = D_N * K_N / 4;   // 409,600
    dim3 blk(256);
    dim3 ggrid(D_N / 128, M_PAD / 128); // 10 x 73

    cvt_kernel<<<(HS4 + 255) / 256, blk, 0, stream>>>(hs, hsb, HS4);
    cvt_kernel<<<(W4 + 255) / 256, blk, 0, stream>>>(Wq, W0, W4);
    cvt_kernel<<<(W4 + 255) / 256, blk, 0, stream>>>(Wk, W1, W4);

    mgemm_kernel<0><<<ggrid, blk, 0, stream>>>(hsb, W0, bq, fc, fs, qb);
    cvt_kernel<<<(W4 + 255) / 256, blk, 0, stream>>>(Wv, W0, W4); // after GEMM0 (stream order)
    mgemm_kernel<1><<<ggrid, blk, 0, stream>>>(hsb, W1, bk, fc, fs, kb);
    mgemm_kernel<2><<<ggrid, blk, 0, stream>>>(hsb, W0, bv, fc, fs, vt);
    cvt_kernel<<<(W4 + 255) / 256, blk, 0, stream>>>(Wo, W1, W4);

    fattn_kernel<<<dim3(10, B_N * H_N), blk, 0, stream>>>(qb, kb, vt, hsb /*= at*/);

    mgemm_kernel<3><<<ggrid, blk, 0, stream>>>(hsb, W1, bo, fc, fs, out);
}